// Round 2
// baseline (61.798 us; speedup 1.0000x reference)
//
#include <hip/hip_runtime.h>

// Persistence image: out[b,d,i,j] = sum_p w_p * exp(-50*((x_i-birth_p)^2 + (y_j-pers_p)^2))
// with w_p = max(pers_p, 0), pers_p = death_p - birth_p, x_i = i/19, y_j = j/19.
//
// v3: SINGLE dispatch, no memset, no atomics. Grid = n_bd * 2 (output i-halves);
// each block streams all 2048 points of its (b,d) through transposed LDS tables
// in 4 chunks of 512, accumulates its 200 cells in registers (8 wave-groups over
// slot-eighths, 4 cells/thread), LDS-reduces across waves, and writes each output
// cell exactly once with a plain store. Removes: memset dispatch, 307K global
// atomics, one set of launch gaps.

#define RX 20
#define RY 20
#define NPTS 2048
#define THREADS 512
#define CHUNK 512
#define NCHUNK (NPTS / CHUNK)   // 4
#define PST 516                 // table slot-stride: mult of 4; 516%32==4 -> row banks spread

__global__ __launch_bounds__(THREADS) void pimg_kernel(const float2* __restrict__ pd,
                                                       float* __restrict__ out) {
    __shared__ __attribute__((aligned(16))) float s_gxT[RX * PST]; // [i][slot], w*exp(-50(x_i-b)^2)
    __shared__ __attribute__((aligned(16))) float s_gyT[RY * PST]; // [j][slot],   exp(-50(y_j-p)^2)
    __shared__ float2 s_pts[CHUNK];       // compacted (birth, pers)
    __shared__ float  s_red[7 * 250];     // waves 1..7 partials, stride 5 (conflict-free)
    __shared__ int    s_wave_cnt[8];

    const int tid  = threadIdx.x;
    const int bd   = blockIdx.x >> 1;
    const int ih   = blockIdx.x & 1;       // which i-decade this block owns
    const int lane = tid & 63;
    const int wid  = tid >> 6;             // 8 waves

    // upfront coalesced load of all 2048 points (4 float2 per thread)
    const float2* base = pd + bd * NPTS;
    float2 p[NCHUNK];
    #pragma unroll
    for (int k = 0; k < NCHUNK; ++k) p[k] = base[k * CHUNK + tid];

    // phase-2 cell tile (valid for lane < 50): rows i0,i0+5 x cols j0,j0+10
    const int i0 = ih * 10 + (lane / 10);
    const int j0 = lane % 10;
    float a00 = 0.0f, a01 = 0.0f, a10 = 0.0f, a11 = 0.0f;

    for (int c = 0; c < NCHUNK; ++c) {
        // ---- compact active points (pers > 0) of this chunk into s_pts
        float birth = p[c].x;
        float pers  = p[c].y - p[c].x;
        bool active = pers > 0.0f;
        unsigned long long mask = __ballot(active);
        if (lane == 0) s_wave_cnt[wid] = __popcll(mask);
        __syncthreads();

        int offset = 0, total = 0;
        #pragma unroll
        for (int w = 0; w < 8; ++w) {
            int cnt = s_wave_cnt[w];
            if (w < wid) offset += cnt;
            total += cnt;
        }
        int tp = (total + 3) & ~3;          // pad to mult of 4 for float4 phase 2
        if (active) {
            int rank = __popcll(mask & ((1ull << lane) - 1ull));
            s_pts[offset + rank] = make_float2(birth, pers);
        }
        if (tid >= total && tid < tp)       // pad slots: pers=0 -> gxw row = 0
            s_pts[tid] = make_float2(0.0f, 0.0f);
        __syncthreads();

        // ---- build transposed tables: 2 threads per slot, 10 i's each (all lanes useful)
        {
            const int ibase = (tid & 1) * 10;
            for (int s = tid >> 1; s < tp; s += THREADS / 2) {
                float2 bp = s_pts[s];
                float b = bp.x, q = bp.y;
                #pragma unroll
                for (int ii = 0; ii < 10; ++ii) {
                    int i = ibase + ii;
                    float xi = i * (1.0f / 19.0f);
                    float dx = xi - b;
                    float dy = xi - q;
                    s_gxT[i * PST + s] = q * __expf(-50.0f * dx * dx);
                    s_gyT[i * PST + s] =     __expf(-50.0f * dy * dy);
                }
            }
        }
        __syncthreads();

        // ---- accumulate: wave wid owns an eighth of the slots; 4 b128 reads / 16 fma per 4 slots
        if (lane < 50) {
            int qs = (((tp + 7) >> 3) + 3) & ~3;   // ceil(tp/8) rounded up to mult of 4
            int s0 = wid * qs; if (s0 > tp) s0 = tp;
            int s1 = s0 + qs;  if (s1 > tp) s1 = tp;
            const float* gxa = &s_gxT[ i0       * PST];
            const float* gxb = &s_gxT[(i0 + 5)  * PST];
            const float* gya = &s_gyT[ j0       * PST];
            const float* gyb = &s_gyT[(j0 + 10) * PST];
            for (int s = s0; s < s1; s += 4) {
                float4 xa = *(const float4*)(gxa + s);
                float4 xb = *(const float4*)(gxb + s);
                float4 ya = *(const float4*)(gya + s);
                float4 yb = *(const float4*)(gyb + s);
                a00 = fmaf(xa.x, ya.x, a00); a00 = fmaf(xa.y, ya.y, a00);
                a00 = fmaf(xa.z, ya.z, a00); a00 = fmaf(xa.w, ya.w, a00);
                a01 = fmaf(xa.x, yb.x, a01); a01 = fmaf(xa.y, yb.y, a01);
                a01 = fmaf(xa.z, yb.z, a01); a01 = fmaf(xa.w, yb.w, a01);
                a10 = fmaf(xb.x, ya.x, a10); a10 = fmaf(xb.y, ya.y, a10);
                a10 = fmaf(xb.z, ya.z, a10); a10 = fmaf(xb.w, ya.w, a10);
                a11 = fmaf(xb.x, yb.x, a11); a11 = fmaf(xb.y, yb.y, a11);
                a11 = fmaf(xb.z, yb.z, a11); a11 = fmaf(xb.w, yb.w, a11);
            }
        }
        __syncthreads();   // protect table/s_pts overwrite by next chunk
    }

    // ---- cross-wave reduction, then one plain store per output cell
    if (wid > 0 && lane < 50) {
        float* r = &s_red[(wid - 1) * 250 + lane * 5];
        r[0] = a00; r[1] = a01; r[2] = a10; r[3] = a11;
    }
    __syncthreads();
    if (wid == 0 && lane < 50) {
        #pragma unroll
        for (int w = 0; w < 7; ++w) {
            const float* r = &s_red[w * 250 + lane * 5];
            a00 += r[0]; a01 += r[1]; a10 += r[2]; a11 += r[3];
        }
        float* o = out + bd * (RX * RY);
        o[ i0       * RY + j0]      = a00;
        o[ i0       * RY + j0 + 10] = a01;
        o[(i0 + 5)  * RY + j0]      = a10;
        o[(i0 + 5)  * RY + j0 + 10] = a11;
    }
}

extern "C" void kernel_launch(void* const* d_in, const int* in_sizes, int n_in,
                              void* d_out, int out_size, void* d_ws, size_t ws_size,
                              hipStream_t stream) {
    const float2* pd = (const float2*)d_in[0];
    float* out = (float*)d_out;
    int n_bd = in_sizes[0] / (2048 * 2);   // 32*3 = 96
    pimg_kernel<<<dim3(n_bd * 2), dim3(THREADS), 0, stream>>>(pd, out);
}

// Round 3
// 60.500 us; speedup vs baseline: 1.0215x; 1.0215x over previous
//
#include <hip/hip_runtime.h>

// Persistence image: out[b,d,i,j] = sum_p w_p * exp(-50*((x_i-birth_p)^2 + (y_j-pers_p)^2))
// with w_p = max(pers_p, 0), pers_p = death_p - birth_p, x_i = i/19, y_j = j/19.
//
// v4 = v2 skeleton (768 blocks, 3/CU, memset+atomics — proven best) with:
//  - phase 1: compact to s_pts, rebuild 2 threads/slot (all lanes useful) using the
//    Gaussian ratio recurrence: f(d+h)=f(d)*g(d), g(d+h)=g(d)*c, c=exp(-100h^2).
//    4 exps + 4 muls/row per thread instead of 20 exps per active thread.
//  - phase 2: 2x4 register tiles (50 lanes x 4 waves over slot-quarters):
//    6 ds_read_b128 per 8 cells vs 4 per 4 -> 25% fewer LDS bytes.

#define RX 20
#define RY 20
#define SPLIT 8        // blocks per (b,d); 96*8 = 768 = 3 blocks/CU exactly
#define CHUNK 256      // points per block
#define PST 260        // slot stride: mult of 4, 260%32==4 -> row banks spread
#define H (1.0f / 19.0f)

#define FMA4(acc, xv, yv)                                        \
    acc = fmaf(xv.x, yv.x, acc); acc = fmaf(xv.y, yv.y, acc);    \
    acc = fmaf(xv.z, yv.z, acc); acc = fmaf(xv.w, yv.w, acc);

__global__ __launch_bounds__(256) void pimg_kernel(const float2* __restrict__ pd,
                                                   float* __restrict__ out,
                                                   int n_bd) {
    __shared__ __attribute__((aligned(16))) float s_gxT[RX * PST]; // [i][slot] w*exp(-50(x_i-b)^2)
    __shared__ __attribute__((aligned(16))) float s_gyT[RY * PST]; // [j][slot]   exp(-50(y_j-p)^2)
    __shared__ float2 s_pts[CHUNK];
    __shared__ float  s_red[3 * 50 * 9];   // waves 1..3 partials, stride 9 (gcd(9,32)=1)
    __shared__ int    s_wave_cnt[4];

    const int tid  = threadIdx.x;
    const int lane = tid & 63;
    const int wid  = tid >> 6;
    const int bd    = blockIdx.x / SPLIT;
    const int chunk = blockIdx.x % SPLIT;
    const int pbase = bd * 2048 + chunk * CHUNK;

    // ---- Phase 0: load + compact active (pers>0) points into s_pts
    float2 p2   = pd[pbase + tid];       // coalesced 8B/lane
    float birth = p2.x;
    float pers  = p2.y - p2.x;
    bool active = pers > 0.0f;

    unsigned long long mask = __ballot(active);
    if (lane == 0) s_wave_cnt[wid] = __popcll(mask);
    __syncthreads();

    int offset = 0, total = 0;
    #pragma unroll
    for (int w = 0; w < 4; ++w) {
        int c = s_wave_cnt[w];
        if (w < wid) offset += c;
        total += c;
    }
    int tp = (total + 3) & ~3;           // pad to mult of 4 for float4 phase 2
    if (active) {
        int rank = __popcll(mask & ((1ull << lane) - 1ull));
        s_pts[offset + rank] = make_float2(birth, pers);
    }
    if (tid >= total && tid < tp)        // pad: q=0 -> gx row 0 -> contributes 0
        s_pts[tid] = make_float2(0.0f, 0.0f);
    __syncthreads();

    // ---- Phase 1: build transposed tables, 2 threads/slot, ratio recurrence
    {
        const int ibase = (tid & 1) * 10;
        const float rc = __expf(-100.0f * H * H);   // constant ratio-of-ratios
        for (int s = tid >> 1; s < tp; s += 128) {
            float2 bp = s_pts[s];
            float b = bp.x, q = bp.y;
            float dx = ibase * H - b;
            float dy = ibase * H - q;
            float fx = __expf(-50.0f * dx * dx);
            float fy = __expf(-50.0f * dy * dy);
            float gx = __expf(-100.0f * H * dx - 50.0f * H * H);
            float gy = __expf(-100.0f * H * dy - 50.0f * H * H);
            #pragma unroll
            for (int ii = 0; ii < 10; ++ii) {
                // writes: banks (4*(ibase+ii)+s)%32, even/odd lanes 2-way max (free)
                s_gxT[(ibase + ii) * PST + s] = q * fx;
                s_gyT[(ibase + ii) * PST + s] = fy;
                fx *= gx; gx *= rc;
                fy *= gy; gy *= rc;
            }
        }
    }
    __syncthreads();

    // ---- Phase 2: 2x4 cell tile per lane (lane<50), wave wid owns a slot-quarter
    float a[2][4] = {{0.0f, 0.0f, 0.0f, 0.0f}, {0.0f, 0.0f, 0.0f, 0.0f}};
    const int i0 = lane / 5;             // rows i0, i0+10
    const int j0 = lane % 5;             // cols j0, j0+5, j0+10, j0+15
    if (lane < 50) {
        int qs = (((tp + 3) >> 2) + 3) & ~3;
        int s0 = wid * qs; if (s0 > tp) s0 = tp;
        int s1 = s0 + qs;  if (s1 > tp) s1 = tp;
        const float* gxa = &s_gxT[ i0        * PST];
        const float* gxb = &s_gxT[(i0 + 10)  * PST];
        const float* gy0 = &s_gyT[ j0        * PST];
        const float* gy1 = &s_gyT[(j0 + 5)   * PST];
        const float* gy2 = &s_gyT[(j0 + 10)  * PST];
        const float* gy3 = &s_gyT[(j0 + 15)  * PST];
        for (int s = s0; s < s1; s += 4) {
            float4 xa = *(const float4*)(gxa + s);
            float4 xb = *(const float4*)(gxb + s);
            float4 y0 = *(const float4*)(gy0 + s);
            float4 y1 = *(const float4*)(gy1 + s);
            float4 y2 = *(const float4*)(gy2 + s);
            float4 y3 = *(const float4*)(gy3 + s);
            FMA4(a[0][0], xa, y0); FMA4(a[0][1], xa, y1);
            FMA4(a[0][2], xa, y2); FMA4(a[0][3], xa, y3);
            FMA4(a[1][0], xb, y0); FMA4(a[1][1], xb, y1);
            FMA4(a[1][2], xb, y2); FMA4(a[1][3], xb, y3);
        }
    }

    // ---- cross-wave reduction (waves 1..3 -> wave 0), then 8 atomics per lane
    if (wid > 0 && lane < 50) {
        float* r = &s_red[(wid - 1) * 450 + lane * 9];
        #pragma unroll
        for (int k = 0; k < 8; ++k) r[k] = a[k >> 2][k & 3];
    }
    __syncthreads();
    if (wid == 0 && lane < 50) {
        #pragma unroll
        for (int w = 0; w < 3; ++w) {
            const float* r = &s_red[w * 450 + lane * 9];
            #pragma unroll
            for (int k = 0; k < 8; ++k) a[k >> 2][k & 3] += r[k];
        }
        float* o = out + bd * (RX * RY);
        #pragma unroll
        for (int rr = 0; rr < 2; ++rr)
            #pragma unroll
            for (int cc = 0; cc < 4; ++cc)
                atomicAdd(o + (i0 + 10 * rr) * RY + (j0 + 5 * cc), a[rr][cc]);
    }
}

extern "C" void kernel_launch(void* const* d_in, const int* in_sizes, int n_in,
                              void* d_out, int out_size, void* d_ws, size_t ws_size,
                              hipStream_t stream) {
    const float2* pd = (const float2*)d_in[0];
    float* out = (float*)d_out;
    int n_bd = in_sizes[0] / (2048 * 2);   // 32*3 = 96
    hipMemsetAsync(d_out, 0, (size_t)out_size * sizeof(float), stream);
    pimg_kernel<<<dim3(n_bd * SPLIT), dim3(256), 0, stream>>>(pd, out, n_bd);
}

// Round 4
// 59.013 us; speedup vs baseline: 1.0472x; 1.0252x over previous
//
#include <hip/hip_runtime.h>

// Persistence image: out[b,d,i,j] = sum_p w_p * exp(-50*((x_i-birth_p)^2 + (y_j-pers_p)^2))
// with w_p = max(pers_p, 0), pers_p = death_p - birth_p, x_i = i/19, y_j = j/19.
//
// v5 = revert to v2, the best-measured variant (59.0 us, absmax 0.0).
// Rationale: 4 rounds of structural variants (single-dispatch, no-atomics,
// -25% LDS traffic, 2x fewer exps) all land within +-1.5 us of 60 us; the
// measurement is dominated by the harness's 256 MiB re-poison fill (40.4 us,
// 83% HBM peak) + fixed graph machinery (~13 us, dispatch-count-invariant per
// v3). v2 is the fastest AND bitwise-exact (no exp reassociation).
//
// Structure: 768 blocks (3/CU), 256 thr. Phase 1: per-point separable Gaussian
// tables, transposed (point-minor) in LDS. Phase 2: 2x2 cell tile per thread,
// float4 LDS reads (4 points per ds_read_b128), slot range split across wave
// pairs, LDS reduction, 4 atomics per owning thread.

#define RX 20
#define RY 20
#define SPLIT 8        // blocks per (b,d); 96*8 = 768 = 3 blocks/CU exactly
#define CHUNK 256      // points per block (one per thread in phase 1)
#define PST 260        // transposed row stride in floats: 16B-aligned, 260%32=4

__global__ __launch_bounds__(256) void pimg_kernel(const float2* __restrict__ pd,
                                                   float* __restrict__ out,
                                                   int n_bd) {
    __shared__ __attribute__((aligned(16))) float s_gxT[RX * PST]; // [i][slot]
    __shared__ __attribute__((aligned(16))) float s_gyT[RY * PST]; // [j][slot]
    __shared__ int s_wave_cnt[4];
    __shared__ float s_red[100 * 5];   // stride 5: conflict-free scalar exchange

    const int tid   = threadIdx.x;
    const int bd    = blockIdx.x / SPLIT;
    const int chunk = blockIdx.x % SPLIT;
    const int pbase = bd * 2048 + chunk * CHUNK;

    // ---- Phase 1: load one point per thread, compact active (pers>0) into LDS tables
    float2 p2  = pd[pbase + tid];        // (birth, death), coalesced 8B/lane
    float birth = p2.x;
    float pers  = p2.y - p2.x;
    bool active = pers > 0.0f;

    unsigned long long mask = __ballot(active);
    int lane = tid & 63;
    int wid  = tid >> 6;
    int rank = __popcll(mask & ((1ull << lane) - 1ull));
    if (lane == 0) s_wave_cnt[wid] = __popcll(mask);
    __syncthreads();

    int offset = 0;
    #pragma unroll
    for (int w = 0; w < 4; ++w)
        if (w < wid) offset += s_wave_cnt[w];
    int total = s_wave_cnt[0] + s_wave_cnt[1] + s_wave_cnt[2] + s_wave_cnt[3];
    int tp = (total + 3) & ~3;           // pad to multiple of 4 for float4 phase 2

    if (active) {
        int slot = offset + rank;        // lanes write consecutive slots: conflict-free
        #pragma unroll
        for (int i = 0; i < RX; ++i) {
            float xi = i * (1.0f / 19.0f);
            float dx = xi - birth;
            float dy = xi - pers;
            s_gxT[i * PST + slot] = pers * __expf(-50.0f * dx * dx);
            s_gyT[i * PST + slot] =        __expf(-50.0f * dy * dy);
        }
    }
    // zero the pad slots [total, tp) so the float4 tail contributes exactly 0
    if (tid >= total && tid < tp) {
        #pragma unroll
        for (int i = 0; i < RX; ++i) {
            s_gxT[i * PST + tid] = 0.0f;
            s_gyT[i * PST + tid] = 0.0f;
        }
    }
    __syncthreads();

    // ---- Phase 2: 2x2 cell tile per thread; slot range split across wave pairs.
    // threads 0..99   (waves 0-1): slots [0, s_mid)
    // threads 128..227 (waves 2-3): slots [s_mid, tp)
    const int half = tid >> 7;
    const int t100 = tid & 127;
    float a00 = 0.0f, a01 = 0.0f, a10 = 0.0f, a11 = 0.0f;
    int ig = 0, jg = 0;
    if (t100 < 100) {
        ig = t100 / 10;                  // gx rows ig, ig+10: bank groups 4ig, 4ig+8 (distinct)
        jg = t100 % 10;                  // gy rows jg, jg+10: worst 2-way (free)
        int s_mid = (tp >> 1) & ~3;
        int s0 = half ? s_mid : 0;
        int s1 = half ? tp    : s_mid;
        const float* gxa = &s_gxT[ ig       * PST];
        const float* gxb = &s_gxT[(ig + 10) * PST];
        const float* gya = &s_gyT[ jg       * PST];
        const float* gyb = &s_gyT[(jg + 10) * PST];
        for (int s = s0; s < s1; s += 4) {
            float4 xa = *(const float4*)(gxa + s);
            float4 xb = *(const float4*)(gxb + s);
            float4 ya = *(const float4*)(gya + s);
            float4 yb = *(const float4*)(gyb + s);
            a00 = fmaf(xa.x, ya.x, a00); a00 = fmaf(xa.y, ya.y, a00);
            a00 = fmaf(xa.z, ya.z, a00); a00 = fmaf(xa.w, ya.w, a00);
            a01 = fmaf(xa.x, yb.x, a01); a01 = fmaf(xa.y, yb.y, a01);
            a01 = fmaf(xa.z, yb.z, a01); a01 = fmaf(xa.w, yb.w, a01);
            a10 = fmaf(xb.x, ya.x, a10); a10 = fmaf(xb.y, ya.y, a10);
            a10 = fmaf(xb.z, ya.z, a10); a10 = fmaf(xb.w, ya.w, a10);
            a11 = fmaf(xb.x, yb.x, a11); a11 = fmaf(xb.y, yb.y, a11);
            a11 = fmaf(xb.z, yb.z, a11); a11 = fmaf(xb.w, yb.w, a11);
        }
    }
    // upper wave-pair hands its partials to the lower one
    if (half == 1 && t100 < 100) {
        s_red[t100 * 5 + 0] = a00;
        s_red[t100 * 5 + 1] = a01;
        s_red[t100 * 5 + 2] = a10;
        s_red[t100 * 5 + 3] = a11;
    }
    __syncthreads();
    if (half == 0 && t100 < 100) {
        a00 += s_red[t100 * 5 + 0];
        a01 += s_red[t100 * 5 + 1];
        a10 += s_red[t100 * 5 + 2];
        a11 += s_red[t100 * 5 + 3];
        float* o = out + bd * (RX * RY);
        atomicAdd(o +  ig       * RY + jg,      a00);
        atomicAdd(o +  ig       * RY + jg + 10, a01);
        atomicAdd(o + (ig + 10) * RY + jg,      a10);
        atomicAdd(o + (ig + 10) * RY + jg + 10, a11);
    }
}

extern "C" void kernel_launch(void* const* d_in, const int* in_sizes, int n_in,
                              void* d_out, int out_size, void* d_ws, size_t ws_size,
                              hipStream_t stream) {
    const float2* pd = (const float2*)d_in[0];
    float* out = (float*)d_out;
    int n_bd = in_sizes[0] / (2048 * 2);   // 32*3 = 96
    hipMemsetAsync(d_out, 0, (size_t)out_size * sizeof(float), stream);
    pimg_kernel<<<dim3(n_bd * SPLIT), dim3(256), 0, stream>>>(pd, out, n_bd);
}